// Round 1
// baseline (782.052 us; speedup 1.0000x reference)
//
#include <hip/hip_runtime.h>
#include <hip/hip_bf16.h>
#include <hip/hip_fp16.h>

// Problem dims
#define A_DIM 4608   // C*9 patch-feature rows
#define L_DIM 4096   // (H/3)*(W/3) spatial columns
#define CH    512
#define H_DIM 192
#define W_DIM 192

typedef _Float16 half8 __attribute__((ext_vector_type(8)));
typedef float   floatx4 __attribute__((ext_vector_type(4)));

// ---------------------------------------------------------------------------
// Pass 1: unfold(x) -> row-major (A_DIM x L_DIM) f16 hi/lo split + 1/row-norm.
// One block per unfold row a = c*9 + kh*3 + kw; column l = ph*64 + pw maps to
// x[c, 3*ph+kh, 3*pw+kw].
// ---------------------------------------------------------------------------
__global__ __launch_bounds__(256) void prep_kernel(
    const float* __restrict__ x,
    _Float16* __restrict__ Uhi,
    _Float16* __restrict__ Ulo,
    float* __restrict__ nrecip) {
  const int a = blockIdx.x;
  const int c = a / 9, k = a % 9;
  const int kh = k / 3, kw = k % 3;
  const float* xc = x + (size_t)c * (H_DIM * W_DIM) + kh * W_DIM + kw;
  const int t = threadIdx.x;
  float ss = 0.f;
#pragma unroll
  for (int it = 0; it < 16; ++it) {
    const int l = it * 256 + t;
    const int ph = l >> 6, pw = l & 63;
    const float v = xc[(3 * ph) * W_DIM + 3 * pw];
    ss += v * v;
    const _Float16 hi = (_Float16)v;
    const _Float16 lo = (_Float16)(v - (float)hi);
    Uhi[(size_t)a * L_DIM + l] = hi;
    Ulo[(size_t)a * L_DIM + l] = lo;
  }
  // block reduction of sum of squares
#pragma unroll
  for (int off = 32; off > 0; off >>= 1) ss += __shfl_down(ss, off, 64);
  __shared__ float wss[4];
  const int wid = t >> 6, lane = t & 63;
  if (lane == 0) wss[wid] = ss;
  __syncthreads();
  if (t == 0) {
    const float tot = wss[0] + wss[1] + wss[2] + wss[3];
    nrecip[a] = 1.0f / sqrtf(tot);
  }
}

// ---------------------------------------------------------------------------
// Pass 2: D[i,j] = sty_i . img_j via 3-term f16-split MFMA (hi*hi+hi*lo+lo*hi),
// fused column-wise max/argmax of v = img_nr[i] * D[i,j] into packed atomics.
// m97 structure: 128x128 tile, BK=32, global_load_lds width-16 staging.
// ---------------------------------------------------------------------------
#define GLDS(g, l)                                                          \
  __builtin_amdgcn_global_load_lds(                                        \
      (const __attribute__((address_space(1))) void*)(g),                   \
      (__attribute__((address_space(3))) void*)(l), 16, 0, 0)

__global__ __launch_bounds__(256) void gemm_max_kernel(
    const _Float16* __restrict__ Shi, const _Float16* __restrict__ Slo,
    const _Float16* __restrict__ Ihi, const _Float16* __restrict__ Ilo,
    const float* __restrict__ img_nr,
    unsigned long long* __restrict__ packed) {
  __shared__ _Float16 sAh[128 * 32];
  __shared__ _Float16 sAl[128 * 32];
  __shared__ _Float16 sBh[128 * 32];
  __shared__ _Float16 sBl[128 * 32];

  const int t = threadIdx.x;
  const int lane = t & 63, wv = t >> 6;
  const int wr = wv >> 1, wc = wv & 1;           // 2x2 waves over 128x128 tile
  const int row0 = blockIdx.y * 128;             // sty rows (i)
  const int col0 = blockIdx.x * 128;             // img rows (j)
  const int quad = lane >> 4;
  const int l15 = lane & 15;

  floatx4 acc[4][4];
#pragma unroll
  for (int rf = 0; rf < 4; ++rf)
#pragma unroll
    for (int cf = 0; cf < 4; ++cf) acc[rf][cf] = (floatx4)0.f;

  // staging map: thread t loads 16B segments for rows (t>>2) and (t>>2)+64
  const int sr = t >> 2, sseg = t & 3;
  const size_t gA = (size_t)(row0 + sr) * L_DIM + sseg * 8;
  const size_t gB = (size_t)(col0 + sr) * L_DIM + sseg * 8;
  const int lofs = sr * 32 + sseg * 8;  // halves; == t*16 bytes (lane-contig)
  const size_t rskip = (size_t)64 * L_DIM;

  for (int k0 = 0; k0 < L_DIM; k0 += 32) {
    __syncthreads();  // previous compute done before overwrite
    GLDS(Shi + gA + k0,         &sAh[lofs]);
    GLDS(Shi + gA + k0 + rskip, &sAh[lofs + 2048]);
    GLDS(Slo + gA + k0,         &sAl[lofs]);
    GLDS(Slo + gA + k0 + rskip, &sAl[lofs + 2048]);
    GLDS(Ihi + gB + k0,         &sBh[lofs]);
    GLDS(Ihi + gB + k0 + rskip, &sBh[lofs + 2048]);
    GLDS(Ilo + gB + k0,         &sBl[lofs]);
    GLDS(Ilo + gB + k0 + rskip, &sBl[lofs + 2048]);
    __syncthreads();  // loads visible

    half8 ah[4], al[4], bh[4], bl[4];
#pragma unroll
    for (int rf = 0; rf < 4; ++rf) {
      const int off = (wr * 64 + rf * 16 + l15) * 32 + quad * 8;
      ah[rf] = *(const half8*)&sAh[off];
      al[rf] = *(const half8*)&sAl[off];
    }
#pragma unroll
    for (int cf = 0; cf < 4; ++cf) {
      const int off = (wc * 64 + cf * 16 + l15) * 32 + quad * 8;
      bh[cf] = *(const half8*)&sBh[off];
      bl[cf] = *(const half8*)&sBl[off];
    }
#pragma unroll
    for (int rf = 0; rf < 4; ++rf)
#pragma unroll
      for (int cf = 0; cf < 4; ++cf) {
        acc[rf][cf] = __builtin_amdgcn_mfma_f32_16x16x32_f16(ah[rf], bh[cf], acc[rf][cf], 0, 0, 0);
        acc[rf][cf] = __builtin_amdgcn_mfma_f32_16x16x32_f16(ah[rf], bl[cf], acc[rf][cf], 0, 0, 0);
        acc[rf][cf] = __builtin_amdgcn_mfma_f32_16x16x32_f16(al[rf], bh[cf], acc[rf][cf], 0, 0, 0);
      }
  }

  // Epilogue: v[i,j] = img_nr[i] * D[i,j]; column-wise max+argmax (first-index
  // tie-break). C/D layout: row = quad*4 + reg, col = lane&15.
  float nr[4][4];
#pragma unroll
  for (int rf = 0; rf < 4; ++rf) {
    const int i = row0 + wr * 64 + rf * 16 + quad * 4;
    const floatx4 n4 = *(const floatx4*)&img_nr[i];
#pragma unroll
    for (int r = 0; r < 4; ++r) nr[rf][r] = n4[r];
  }
#pragma unroll
  for (int cf = 0; cf < 4; ++cf) {
    const int j = col0 + wc * 64 + cf * 16 + l15;
    float best = -3.4e38f;
    int bi = 0x7FFFFFFF;
#pragma unroll
    for (int rf = 0; rf < 4; ++rf)
#pragma unroll
      for (int r = 0; r < 4; ++r) {
        const int i = row0 + wr * 64 + rf * 16 + quad * 4 + r;
        const float v = acc[rf][cf][r] * nr[rf][r];
        if (v > best) { best = v; bi = i; }   // ascending i => first-index wins
      }
    // reduce across the 4 quads holding this column
#pragma unroll
    for (int off = 16; off < 64; off <<= 1) {
      const float ov = __shfl_xor(best, off, 64);
      const int oi = __shfl_xor(bi, off, 64);
      if (ov > best || (ov == best && oi < bi)) { best = ov; bi = oi; }
    }
    if (quad == 0) {
      const unsigned u = __float_as_uint(best);
      const unsigned key = (u & 0x80000000u) ? ~u : (u | 0x80000000u);
      const unsigned long long pk =
          ((unsigned long long)key << 32) | (unsigned)(~(unsigned)bi);
      atomicMax(&packed[j], pk);
    }
  }
}

// ---------------------------------------------------------------------------
// Pass 3: decode packed (max over i of img_nr[i]*D[i,j]), apply sty_nr[j],
// write outputs: out[0..A) = nearest (as float), out[A..2A) = max_sim.
// ---------------------------------------------------------------------------
__global__ __launch_bounds__(256) void finalize_kernel(
    const unsigned long long* __restrict__ packed,
    const float* __restrict__ sty_nr, float* __restrict__ out) {
  const int j = blockIdx.x * 256 + threadIdx.x;
  if (j >= A_DIM) return;
  const unsigned long long p = packed[j];
  const unsigned key = (unsigned)(p >> 32);
  const unsigned u = (key & 0x80000000u) ? (key ^ 0x80000000u) : ~key;
  const float v = __uint_as_float(u);
  const int idx = (int)(~(unsigned)(p & 0xFFFFFFFFu));
  out[j] = (float)idx;
  out[A_DIM + j] = v * sty_nr[j];
}

extern "C" void kernel_launch(void* const* d_in, const int* in_sizes, int n_in,
                              void* d_out, int out_size, void* d_ws, size_t ws_size,
                              hipStream_t stream) {
  const float* model = (const float*)d_in[0];  // img side
  const float* style = (const float*)d_in[1];  // sty side
  float* out = (float*)d_out;
  char* ws = (char*)d_ws;

  const size_t usz = (size_t)A_DIM * L_DIM * 2;  // one f16 matrix: 37,748,736 B
  _Float16* img_hi = (_Float16*)(ws);
  _Float16* img_lo = (_Float16*)(ws + usz);
  _Float16* sty_hi = (_Float16*)(ws + 2 * usz);
  _Float16* sty_lo = (_Float16*)(ws + 3 * usz);
  float* img_nr = (float*)(ws + 4 * usz);
  float* sty_nr = img_nr + A_DIM;
  unsigned long long* packed = (unsigned long long*)(img_nr + 2 * A_DIM);

  hipMemsetAsync(packed, 0, (size_t)A_DIM * 8, stream);
  prep_kernel<<<A_DIM, 256, 0, stream>>>(model, img_hi, img_lo, img_nr);
  prep_kernel<<<A_DIM, 256, 0, stream>>>(style, sty_hi, sty_lo, sty_nr);
  gemm_max_kernel<<<dim3(36, 36), 256, 0, stream>>>(sty_hi, sty_lo, img_hi,
                                                    img_lo, img_nr, packed);
  finalize_kernel<<<18, 256, 0, stream>>>(packed, sty_nr, out);
}